// Round 15
// baseline (91.001 us; speedup 1.0000x reference)
//
#include <hip/hip_runtime.h>

// Chamfer distance, pred/target: (4, 8192, 3) fp32.
// Round-14 structure (measured best, 88.8 us) with two micro-opts:
//  (1) q staged as TWO interleaved 16B-stride LDS arrays -> 2x ds_read_b128
//      per iter (was 4x ds_read_b64 + 4 addr calcs); conflict-free at 16B
//      stride (8 lanes/phase x 16B = 128B distinct banks).
//  (2) #pragma unroll 8 on the jj loop (was 4).

typedef float f32x2 __attribute__((ext_vector_type(2)));
typedef float f32x4 __attribute__((ext_vector_type(4)));

#define NPTS   8192
#define BATCH  4
#define RPT    8                  // register-resident rows per thread
#define BLOCK  256
#define PTILE  (RPT * BLOCK)      // 2048 rows per block
#define NTILES (NPTS / PTILE)     // 4
#define CHUNK  128                // streamed cols per block
#define NPAIR  (CHUNK / 2)        // 64 column pairs
#define NCHUNK (NPTS / CHUNK)     // 64  -> grid 4*64*4 = 1024 blocks (4/CU)
#define NMINS  (2 * BATCH * NPTS) // 65536

__global__ __launch_bounds__(256) void chamfer_init(int* __restrict__ mins)
{
    const int idx = blockIdx.x * 256 + threadIdx.x;       // 16384 int4 slots
    ((int4*)mins)[idx] = make_int4(0x7F7F7F7F, 0x7F7F7F7F,
                                   0x7F7F7F7F, 0x7F7F7F7F);
}

__global__ __launch_bounds__(BLOCK, 4) void chamfer_pairs(
    const float* __restrict__ pred, const float* __restrict__ target,
    int* __restrict__ mins)
{
    __shared__ f32x4 qa4[NPAIR];      // {qx[2j], qx[2j+1], qy[2j], qy[2j+1]}
    __shared__ f32x4 qb4[NPAIR];      // {qz[2j], qz[2j+1], qw[2j], qw[2j+1]}
    __shared__ int   cmin_s[CHUNK];   // per-block column mins (int bits)

    const int b = blockIdx.z;
    const float* __restrict__ P = pred   + b * NPTS * 3;
    const float* __restrict__ Q = target + b * NPTS * 3;

    const int tid = threadIdx.x;
    const int i0  = blockIdx.x * PTILE + tid;
    const int j0  = blockIdx.y * CHUNK;

    if (tid < CHUNK) {
        const float* qp = Q + 3 * (j0 + tid);
        const float qx = qp[0], qy = qp[1], qz = qp[2];
        const int jp = tid >> 1, h = tid & 1;
        ((float*)&qa4[jp])[h]     = qx;
        ((float*)&qa4[jp])[2 + h] = qy;
        ((float*)&qb4[jp])[h]     = qz;
        ((float*)&qb4[jp])[2 + h] = fmaf(qx, qx, fmaf(qy, qy, qz * qz));
        cmin_s[tid] = 0x7F7F7F7F;   // 3.39e38f
    }
    __syncthreads();

    f32x2 pxn2[RPT], pyn2[RPT], pzn2[RPT], p22[RPT];
    float m[RPT];
#pragma unroll
    for (int r = 0; r < RPT; ++r) {
        const float* pp = P + 3 * (i0 + r * BLOCK);
        const float x = pp[0], y = pp[1], z = pp[2];
        const float nx = -2.0f * x, ny = -2.0f * y, nz = -2.0f * z;
        const float p2 = fmaf(x, x, fmaf(y, y, z * z));
        pxn2[r] = (f32x2){nx, nx};
        pyn2[r] = (f32x2){ny, ny};
        pzn2[r] = (f32x2){nz, nz};
        p22[r]  = (f32x2){p2, p2};
        m[r]    = 3.0e38f;
    }

    // per-lane staggered pair index, decorrelated across the 4 waves
    const int soff = (tid & 63) + ((tid >> 6) << 4);

#pragma unroll 8
    for (int jj = 0; jj < NPAIR; ++jj) {
        const int jp = (soff + jj) & (NPAIR - 1);
        const f32x4 a  = qa4[jp];                 // ds_read_b128
        const f32x4 bb = qb4[jp];                 // ds_read_b128
        const f32x2 qx = (f32x2){a.x,  a.y};
        const f32x2 qy = (f32x2){a.z,  a.w};
        const f32x2 qz = (f32x2){bb.x, bb.y};
        const f32x2 qw = (f32x2){bb.z, bb.w};

        f32x2 d[RPT];
#pragma unroll
        for (int r = 0; r < RPT; ++r) {
            f32x2 t = __builtin_elementwise_fma(pxn2[r], qx, qw);  // |q|^2 - 2p.q
            t = __builtin_elementwise_fma(pyn2[r], qy, t);
            t = __builtin_elementwise_fma(pzn2[r], qz, t);
            m[r] = fminf(fminf(m[r], t.x), t.y);   // v_min3, |p|^2 deferred
            d[r] = t + p22[r];                     // v_pk_add: full d^2 pair
        }
        // col-min trees per half, min3-friendly nesting
        const float cl = fminf(
            fminf(fminf(fminf(d[0].x, d[1].x), d[2].x),
                  fminf(fminf(d[3].x, d[4].x), d[5].x)),
            fminf(d[6].x, d[7].x));
        const float ch = fminf(
            fminf(fminf(fminf(d[0].y, d[1].y), d[2].y),
                  fminf(fminf(d[3].y, d[4].y), d[5].y)),
            fminf(d[6].y, d[7].y));
        atomicMin(&cmin_s[2 * jp],     __float_as_int(cl));
        atomicMin(&cmin_s[2 * jp + 1], __float_as_int(ch));
    }

    int* __restrict__ fwd = mins + b * NPTS;
    int* __restrict__ bwd = mins + (BATCH + b) * NPTS;
#pragma unroll
    for (int r = 0; r < RPT; ++r) {
        const float v = fmaxf(m[r] + p22[r].x, 0.0f);  // clamp commutes with min
        atomicMin(&fwd[i0 + r * BLOCK], __float_as_int(v));
    }
    __syncthreads();
    if (tid < CHUNK)
        atomicMin(&bwd[j0 + tid], cmin_s[tid]);
}

__global__ __launch_bounds__(1024) void chamfer_reduce(
    const int* __restrict__ mins, float* __restrict__ out)
{
    __shared__ float part[16];
    // 65536 ints / 1024 threads = 64 each = 16 int4 loads
    const int4* __restrict__ m4 = (const int4*)mins;   // 16384 int4s
    float s = 0.0f;
#pragma unroll 4
    for (int k = 0; k < 16; ++k) {
        const int4 v = m4[k * 1024 + threadIdx.x];
        s += fmaxf(__int_as_float(v.x), 0.0f) + fmaxf(__int_as_float(v.y), 0.0f) +
             fmaxf(__int_as_float(v.z), 0.0f) + fmaxf(__int_as_float(v.w), 0.0f);
    }

    for (int off = 32; off > 0; off >>= 1)
        s += __shfl_down(s, off, 64);
    if ((threadIdx.x & 63) == 0)
        part[threadIdx.x >> 6] = s;
    __syncthreads();

    if (threadIdx.x < 16) {
        float v = part[threadIdx.x];
        for (int off = 8; off > 0; off >>= 1)
            v += __shfl_down(v, off, 64);
        if (threadIdx.x == 0)
            out[0] = v * (1.0f / (float)(BATCH * NPTS));  // /32768
    }
}

extern "C" void kernel_launch(void* const* d_in, const int* in_sizes, int n_in,
                              void* d_out, int out_size, void* d_ws, size_t ws_size,
                              hipStream_t stream)
{
    const float* pred   = (const float*)d_in[0];
    const float* target = (const float*)d_in[1];
    float* out = (float*)d_out;
    int*   mins = (int*)d_ws;   // [2][BATCH][NPTS] fp32-as-int partial mins

    chamfer_init<<<NMINS / 4 / 256, 256, 0, stream>>>(mins);

    dim3 grid(NTILES, NCHUNK, BATCH);
    chamfer_pairs<<<grid, BLOCK, 0, stream>>>(pred, target, mins);
    chamfer_reduce<<<1, 1024, 0, stream>>>(mins, out);
}